// Round 13
// baseline (389.153 us; speedup 1.0000x reference)
//
#include <hip/hip_runtime.h>
#include <hip/hip_bf16.h>
#include <cstdint>
#include <cstddef>

typedef __attribute__((ext_vector_type(8))) short short8;
typedef __attribute__((ext_vector_type(4))) float f32x4;
typedef __attribute__((ext_vector_type(4))) unsigned int u32x4;

#define D_DIM 512
#define K_DIM 4096
#define N_ROWS 16384  // S*B

#define DECAY_F 0.99f
#define OMD_F 0.01f
#define EPS_F 1e-5f
#define COMMIT_F 0.25f
#define MARGIN_F 0.75f

// d_out offsets (floats), return-order concat
#define OFF_LOSS 0
#define OFF_QST 1
#define OFF_ENC (1 + 8388608)            // 8388609
#define OFF_IDX (OFF_ENC + 67108864)     // 75497473
#define OFF_NEW_W (OFF_IDX + 16384)      // 75513857
#define OFF_NEW_CS (OFF_NEW_W + 2097152) // 77611009
#define OFF_NEW_EMA (OFF_NEW_CS + 4096)  // 77615105

// ENC f32x4 span: floats [8388612, 75497472) -> 16777215 vectors; tail float
// 75497472 patched in k_cs; head floats 8388609..11 patched by cleaner 0.
#define ENC4_CNT 16777215
#define CHUNK4 8192  // f32x4 per cleaner chunk (128 KB); 2048 chunks total

// small ws scratch (bytes)
#define WS_MINKEY 0        // u64*16384 = 131072
#define WS_COUNTS 131072   // int*4096
#define WS_E2 147456       // f32*4096
#define WS_LOSSP 163840    // f32*64
#define WS_RCNT 164096     // int (+pad)
#define WS_OFFS 164112     // int*4096
#define WS_CURS 180496     // int*4096
#define WS_ROWL 196880     // int*16384
#define WS_ARENA 262416    // big arena when ws_size allows

// big arena layout (byte offsets within arena, all 16B-aligned)
#define AR_M1K 0           // u64[16384][32] = 4 MB
#define AR_M2V 4194304     // f32[16384][32] = 2 MB
#define AR_XHI 6291456     // bf16[16384][512] = 16 MB
#define AR_EHI 23068672    // bf16[4096][512] = 4 MB
#define AR_RROW 27262976   // int[16384]
#define AR_RCUT 27328512   // f32[16384]
#define AR_NEED 27394048
#define WS_NEED (WS_ARENA + AR_NEED)

// fallback arena inside one-hot region (float offset; byte 16B-aligned)
#define SCR0 8388612

// ---------------- helpers ----------------
__device__ __forceinline__ unsigned long long mkkey(float d, int c) {
  unsigned u = __float_as_uint(d);
  u ^= (unsigned)(((int)u) >> 31) | 0x80000000u;  // monotone total order
  return ((unsigned long long)u << 32) | (unsigned)c;
}
__device__ __forceinline__ float keyval(unsigned long long k) {
  unsigned u = (unsigned)(k >> 32);
  u = (u & 0x80000000u) ? (u ^ 0x80000000u) : ~u;
  return __uint_as_float(u);
}
// merge (k1,v2) with (ko,v2o): second smallest of union = min(max(v1,v1o), v2, v2o)
__device__ __forceinline__ void merge2(unsigned long long& k1, float& v2,
                                       unsigned long long ko, float v2o) {
  float v1 = keyval(k1), v1o = keyval(ko);
  float vmax = fmaxf(v1, v1o);
  v2 = fminf(fminf(v2, v2o), vmax);
  if (ko < k1) k1 = ko;
}
__device__ __forceinline__ unsigned pk2o(float a, float b) {
  unsigned ua = (__float_as_uint(a) + 0x8000u) & 0xFFFF0000u;
  unsigned ub = (__float_as_uint(b) + 0x8000u) & 0xFFFF0000u;
  return (ua >> 16) | ub;
}
__device__ __forceinline__ void gl_lds16(const void* g, void* l) {
  __builtin_amdgcn_global_load_lds(
      (const __attribute__((address_space(1))) unsigned int*)g,
      (__attribute__((address_space(3))) unsigned int*)l, 16, 0, 0);
}

// batched check-and-skip clean of one 128KB ENC chunk (MLP=16 reads, stores
// only to dirty 16B cells; correct for ANY prior buffer state)
__device__ __forceinline__ void enc_chunk(float* __restrict__ out, int cid) {
  const f32x4 z = {0.f, 0.f, 0.f, 0.f};
  const u32x4* p = (const u32x4*)(out + 8388612);
  const int tid = threadIdx.x;
  const int base = cid * CHUNK4 + tid;
#pragma unroll
  for (int h = 0; h < 2; ++h) {
    u32x4 v[16];
#pragma unroll
    for (int t = 0; t < 16; ++t) {
      int i = base + (h * 16 + t) * 256;
      int ii = (i < ENC4_CNT) ? i : 0;
      v[t] = __builtin_nontemporal_load(p + ii);
    }
#pragma unroll
    for (int t = 0; t < 16; ++t) {
      int i = base + (h * 16 + t) * 256;
      if (i < ENC4_CNT && (v[t].x | v[t].y | v[t].z | v[t].w))
        *(f32x4*)(p + i) = z;
    }
  }
  if (cid == 0 && tid == 0) {
    if (__float_as_uint(out[8388609])) out[8388609] = 0.f;
    if (__float_as_uint(out[8388610])) out[8388610] = 0.f;
    if (__float_as_uint(out[8388611])) out[8388611] = 0.f;
  }
}

// ---------- codebook norms + E->bf16 + zero counts/loss/rcnt ----------
__global__ void k_e2(const float* __restrict__ E, float* __restrict__ e2,
                     uint4* __restrict__ ehi, int* __restrict__ counts,
                     float* __restrict__ loss_part, int* __restrict__ rcnt) {
  int tid = threadIdx.x;
  int lane = tid & 63;
  int w = tid >> 6;
  int k = blockIdx.x * 4 + w;
  if (tid < 4) counts[blockIdx.x * 4 + tid] = 0;
  if (blockIdx.x == 0 && tid < 64) loss_part[tid] = 0.f;
  if (blockIdx.x == 1 && tid == 0) *rcnt = 0;
  const float4* ev = (const float4*)(E + (size_t)k * D_DIM);
  float4 a = ev[lane * 2], b = ev[lane * 2 + 1];
  uint4 h;
  h.x = pk2o(a.x, a.y);
  h.y = pk2o(a.z, a.w);
  h.z = pk2o(b.x, b.y);
  h.w = pk2o(b.z, b.w);
  ehi[(size_t)k * 64 + lane] = h;
  float s = a.x * a.x + a.y * a.y + a.z * a.z + a.w * a.w +
            b.x * b.x + b.y * b.y + b.z * b.z + b.w * b.w;
#pragma unroll
  for (int off = 32; off > 0; off >>= 1) s += __shfl_down(s, off, 64);
  if (lane == 0) e2[k] = s;
}

// ---------- f32 -> hi bf16 (8 elems / thread) ----------
__global__ void k_conv(const float* __restrict__ src, uint4* __restrict__ hi) {
  int t = blockIdx.x * 256 + threadIdx.x;
  const float4* s4 = (const float4*)src;
  float4 a = s4[t * 2], b = s4[t * 2 + 1];
  uint4 h;
  h.x = pk2o(a.x, a.y);
  h.y = pk2o(a.z, a.w);
  h.z = pk2o(b.x, b.y);
  h.w = pk2o(b.z, b.w);
  hi[t] = h;
}

// ---------- new_ema_w := DECAY * ema_w (fallback path only) ----------
__global__ void k_scale_emaw(const float* __restrict__ ema_w, float* __restrict__ out) {
  int i = blockIdx.x * 256 + threadIdx.x;
  out[OFF_NEW_EMA + i] = DECAY_F * ema_w[i];
}

// ---------- bf16-hi MFMA distance GEMM + per-block top-2 argmin + cleaners ----------
// main blocks: bx < 128. cleaner blocks: bx in [128,192) -> cid = (bx-128)*32+by
// covering all 2048 chunks (256 MB) with batched check-and-skip.
__global__ __launch_bounds__(256, 2) void k_gemm(
    const char* __restrict__ xhi, const char* __restrict__ ehi,
    const float* __restrict__ e2, unsigned long long* __restrict__ m1k,
    float* __restrict__ m2v, float* outp, int withClean) {
  if (blockIdx.x >= 128) {
    enc_chunk(outp, ((int)blockIdx.x - 128) * 32 + (int)blockIdx.y);
    return;
  }
  extern __shared__ char smem[];  // 65536
  const int tid = threadIdx.x;
  const int w = tid >> 6, lane = tid & 63;
  const int wr = w >> 1, wc = w & 1;
  const int l15 = lane & 15, g = lane >> 4;
  const int row0 = blockIdx.x * 128;
  const int col0 = blockIdx.y * 128;
  (void)withClean;

  const char* srcBase = (w < 2) ? xhi : ehi;
  const int srcRow0 = (w < 2) ? (row0 + 64 * w) : (col0 + 64 * (w - 2));
  const int lr = lane >> 3;  // row within 8-row group
  const int lc = lane & 7;   // dest slot
  const char* srcLane = srcBase + (size_t)(srcRow0 + lr) * 1024 + ((lc ^ lr) << 4);
  const int dstOff = w * 8192;

#define STAGE(c, b)                                       \
  {                                                       \
    const char* sp_ = srcLane + (c) * 128;                \
    char* lb_ = smem + (b) * 32768 + dstOff;              \
    _Pragma("unroll") for (int q = 0; q < 8; ++q)         \
        gl_lds16(sp_ + q * 8192, lb_ + q * 1024);         \
  }

  f32x4 acc[4][4];
  const f32x4 z = {0.f, 0.f, 0.f, 0.f};
#pragma unroll
  for (int i = 0; i < 4; ++i)
#pragma unroll
    for (int j = 0; j < 4; ++j) acc[i][j] = z;

  STAGE(0, 0);
  const int s0 = (g ^ (l15 & 7)) << 4;
  const int aRow = (wr * 64 + l15) * 128;
  const int bRow = (wc * 64 + l15) * 128;

  for (int c = 0; c < 8; ++c) {
    __syncthreads();
    if (c < 7) STAGE(c + 1, (c + 1) & 1);
    const char* Ab = smem + (c & 1) * 32768;
    const char* Bb = Ab + 16384;
    short8 a[2][4], b[2][4];
#pragma unroll
    for (int kk = 0; kk < 2; ++kk) {
      const int sw = s0 ^ (kk << 6);
#pragma unroll
      for (int i = 0; i < 4; ++i) {
        a[kk][i] = *(const short8*)(Ab + aRow + i * 2048 + sw);
        b[kk][i] = *(const short8*)(Bb + bRow + i * 2048 + sw);
      }
    }
#pragma unroll
    for (int kk = 0; kk < 2; ++kk)
#pragma unroll
      for (int i = 0; i < 4; ++i)
#pragma unroll
        for (int j = 0; j < 4; ++j)
          acc[i][j] = __builtin_amdgcn_mfma_f32_16x16x32_bf16(a[kk][i], b[kk][j], acc[i][j], 0, 0, 0);
  }
#undef STAGE

  __syncthreads();
  unsigned long long* lk = (unsigned long long*)smem;  // [128][2]
  float* lv = (float*)(smem + 2048);                   // [128][2]
  float e2v[4];
#pragma unroll
  for (int j = 0; j < 4; ++j) e2v[j] = e2[col0 + wc * 64 + j * 16 + l15];

#pragma unroll
  for (int i = 0; i < 4; ++i) {
    int rowl = wr * 64 + i * 16 + (g << 2);
#pragma unroll
    for (int r = 0; r < 4; ++r) {
      unsigned long long k1 = 0;
      float v2 = 3.4e38f;
#pragma unroll
      for (int j = 0; j < 4; ++j) {
        float dv = fmaf(-2.f, acc[i][j][r], e2v[j]);
        unsigned long long kk = mkkey(dv, col0 + wc * 64 + j * 16 + l15);
        if (j == 0) k1 = kk;
        else merge2(k1, v2, kk, 3.4e38f);
      }
#pragma unroll
      for (int m = 1; m <= 8; m <<= 1) {
        unsigned long long ko = __shfl_xor(k1, m, 64);
        float vo = __shfl_xor(v2, m, 64);
        merge2(k1, v2, ko, vo);
      }
      if (l15 == 0) {
        lk[(rowl + r) * 2 + wc] = k1;
        lv[(rowl + r) * 2 + wc] = v2;
      }
    }
  }
  __syncthreads();
  if (tid < 128) {
    unsigned long long k1 = lk[tid * 2];
    float v2 = lv[tid * 2];
    merge2(k1, v2, lk[tid * 2 + 1], lv[tid * 2 + 1]);
    size_t o = (size_t)(row0 + tid) * 32 + blockIdx.y;
    m1k[o] = k1;
    m2v[o] = v2;
  }
}

// ---------- per-row reduce over 32 blocks; flag near-ties for rescue ----------
__global__ void k_reduce(const unsigned long long* __restrict__ m1k,
                         const float* __restrict__ m2v,
                         unsigned long long* __restrict__ minkey,
                         int* __restrict__ rcnt, int* __restrict__ rrows,
                         float* __restrict__ rcut) {
  int row = blockIdx.x * 256 + threadIdx.x;
  const unsigned long long* kp = m1k + (size_t)row * 32;
  const float* vp = m2v + (size_t)row * 32;
  unsigned long long k1 = kp[0];
  float v2 = vp[0];
#pragma unroll 4
  for (int t = 1; t < 32; ++t) merge2(k1, v2, kp[t], vp[t]);
  float v1 = keyval(k1);
  if (v2 - v1 < MARGIN_F) {
    minkey[row] = ~0ull;  // reset for exact atomicMin
    int p = atomicAdd(rcnt, 1);
    rrows[p] = row;
    rcut[p] = v1 + MARGIN_F;
  } else {
    minkey[row] = k1;
  }
}

// ---------- exact f32 re-scan for flagged rows, filtered by per-block min ----------
__global__ __launch_bounds__(256) void k_rescue(
    const float* __restrict__ flat, const float* __restrict__ E,
    const float* __restrict__ e2, const int* __restrict__ rcnt,
    const int* __restrict__ rrows, const float* __restrict__ rcut,
    const unsigned long long* __restrict__ m1k,
    unsigned long long* __restrict__ minkey) {
  __shared__ float sx[512];
  __shared__ unsigned long long skey[16];
  const int tid = threadIdx.x;
  const int sl = tid & 15;
  int cnt = *rcnt;
  if (cnt > N_ROWS) cnt = N_ROWS;
  for (int j = (int)blockIdx.x; j < cnt; j += (int)gridDim.x) {
    const int row = rrows[j];
    const float cutoff = rcut[j];
    __syncthreads();
    if (tid < 128) ((float4*)sx)[tid] = ((const float4*)(flat + (size_t)row * 512))[tid];
    __syncthreads();
    unsigned long long best = ~0ull;
    for (int b = 0; b < 32; ++b) {
      if (keyval(m1k[(size_t)row * 32 + b]) >= cutoff) continue;
      const int c0 = b * 128 + (tid >> 4);
#pragma unroll 2
      for (int p = 0; p < 8; ++p) {
        const int c = c0 + p * 16;
        const float4* ev = (const float4*)(E + (size_t)c * 512) + sl * 8;
        const float4* xv = (const float4*)sx + sl * 8;
        float s = 0.f;
#pragma unroll
        for (int q = 0; q < 8; ++q) {
          float4 e4 = ev[q];
          float4 x4 = xv[q];
          s = fmaf(e4.x, x4.x, s);
          s = fmaf(e4.y, x4.y, s);
          s = fmaf(e4.z, x4.z, s);
          s = fmaf(e4.w, x4.w, s);
        }
#pragma unroll
        for (int m = 1; m <= 8; m <<= 1) s += __shfl_xor(s, m, 64);
        if (sl == 0) {
          unsigned long long k = mkkey(fmaf(-2.f, s, e2[c]), c);
          if (k < best) best = k;
        }
      }
    }
    if (sl == 0) skey[tid >> 4] = best;
    __syncthreads();
    if (tid == 0) {
      unsigned long long m = skey[0];
#pragma unroll
      for (int t = 1; t < 16; ++t)
        if (skey[t] < m) m = skey[t];
      atomicMin(&minkey[row], m);
    }
  }
}

// ---------- fallback path: bulk zero ----------
__global__ void k_zero(float* __restrict__ out) {
  const f32x4 z = {0.f, 0.f, 0.f, 0.f};
  f32x4* out4 = (f32x4*)(out + 8388612);
#pragma unroll
  for (int t = 0; t < 4; ++t) {
    int i = blockIdx.x * 1024 + t * 256 + threadIdx.x;
    if (i < 16777215) __builtin_nontemporal_store(z, out4 + i);
  }
  if (blockIdx.x == 0 && threadIdx.x == 0) {
    out[8388609] = 0.f;
    out[8388610] = 0.f;
    out[8388611] = 0.f;
    out[75497472] = 0.f;
  }
}

// ---------- counts (LDS histogram) + exclusive prefix -> offs, cursor ----------
__global__ __launch_bounds__(1024) void k_prefix(const unsigned long long* __restrict__ minkey,
                                                 int* __restrict__ counts,
                                                 int* __restrict__ offs,
                                                 int* __restrict__ cursor) {
  __shared__ int lc[4096];
  __shared__ int wsum[16];
  const int tid = threadIdx.x;
  const int lane = tid & 63, w = tid >> 6;
#pragma unroll
  for (int t = 0; t < 4; ++t) lc[tid * 4 + t] = 0;
  __syncthreads();
#pragma unroll
  for (int t = 0; t < 16; ++t) {
    int c = (int)(unsigned)(minkey[tid + 1024 * t] & 0xffffffffull);
    atomicAdd(&lc[c], 1);
  }
  __syncthreads();
  int v[4];
  int loc = 0;
#pragma unroll
  for (int t = 0; t < 4; ++t) {
    v[t] = lc[tid * 4 + t];
    loc += v[t];
  }
  int scan = loc;
#pragma unroll
  for (int off = 1; off <= 32; off <<= 1) {
    int o = __shfl_up(scan, off, 64);
    if (lane >= off) scan += o;
  }
  if (lane == 63) wsum[w] = scan;
  __syncthreads();
  int base = 0;
  for (int i = 0; i < w; ++i) base += wsum[i];
  int run = base + scan - loc;
#pragma unroll
  for (int t = 0; t < 4; ++t) {
    counts[tid * 4 + t] = v[t];
    offs[tid * 4 + t] = run;
    cursor[tid * 4 + t] = run;
    run += v[t];
  }
}

// ---------- scatter row ids into cluster buckets ----------
__global__ void k_scatter(const unsigned long long* __restrict__ minkey,
                          int* __restrict__ cursor, int* __restrict__ rowl) {
  int n = blockIdx.x * 256 + threadIdx.x;
  int c = (int)(unsigned)(minkey[n] & 0xffffffffull);
  int pos = atomicAdd(&cursor[c], 1);
  rowl[pos] = n;
}

// ---------- fused per-code pass: QST + loss + new_ema_w/new_w + IDX + ENC ones ----------
__global__ __launch_bounds__(256) void k_qdw(const float* __restrict__ flat,
                                             const float* __restrict__ E,
                                             const float* __restrict__ ema_w,
                                             const int* __restrict__ counts,
                                             const int* __restrict__ offs,
                                             const int* __restrict__ rowl,
                                             float* __restrict__ out,
                                             float* __restrict__ loss_part) {
  const int k = blockIdx.x;
  const int tid = threadIdx.x;
  const int cnt = counts[k];
  const int off = offs[k];
  const int d0 = tid * 2;
  const float ex = E[(size_t)k * D_DIM + d0];
  const float ey = E[(size_t)k * D_DIM + d0 + 1];
  float s0 = 0.f, s1 = 0.f, lsum = 0.f;
  for (int i = 0; i < cnt; ++i) {
    int r = rowl[off + i];
    const float* xr = flat + (size_t)r * D_DIM + d0;
    float xx = xr[0], xy = xr[1];
    size_t qb = (size_t)OFF_QST + (size_t)r * D_DIM + d0;
    out[qb] = xx + (ex - xx);
    out[qb + 1] = xy + (ey - xy);
    float dx = ex - xx, dy = ey - xy;
    lsum += dx * dx + dy * dy;
    s0 += xx;
    s1 += xy;
  }
  // indices + one-hot ones for this bucket
  for (int i = tid; i < cnt; i += 256) {
    int r = rowl[off + i];
    out[OFF_IDX + r] = (float)k;
    out[(size_t)OFF_ENC + (size_t)r * K_DIM + k] = 1.0f;
  }
  // dw finalize
  float e0 = DECAY_F * ema_w[(size_t)k * D_DIM + d0] + OMD_F * s0;
  float e1 = DECAY_F * ema_w[(size_t)k * D_DIM + d0 + 1] + OMD_F * s1;
  float cs = out[OFF_NEW_CS + k];
  size_t b = (size_t)k * D_DIM + d0;
  out[OFF_NEW_EMA + b] = e0;
  out[OFF_NEW_EMA + b + 1] = e1;
  out[OFF_NEW_W + b] = e0 / cs;
  out[OFF_NEW_W + b + 1] = e1 / cs;
  // loss partial reduce
#pragma unroll
  for (int o = 32; o > 0; o >>= 1) lsum += __shfl_down(lsum, o, 64);
  __shared__ float ws4[4];
  if ((tid & 63) == 0) ws4[tid >> 6] = lsum;
  __syncthreads();
  if (tid == 0 && cnt > 0)
    atomicAdd(&loss_part[k & 63], ws4[0] + ws4[1] + ws4[2] + ws4[3]);
}

// ---------- loss finalize (big path) ----------
__global__ void k_loss(const float* __restrict__ loss_part, float* __restrict__ out) {
  float lv = loss_part[threadIdx.x];
#pragma unroll
  for (int off = 32; off > 0; off >>= 1) lv += __shfl_down(lv, off, 64);
  if (threadIdx.x == 0) out[OFF_LOSS] = COMMIT_F * lv / 8388608.0f;
}

// ---------- gather quantized, STE out, loss partials, dw atomics (fallback) ----------
__global__ void k_quant(const float* __restrict__ flat, const float* __restrict__ E,
                        const unsigned long long* __restrict__ minkey,
                        float* __restrict__ out, float* emaw,
                        float* __restrict__ loss_part) {
  int tid = threadIdx.x;
  int lane = tid & 63;
  int rw = tid >> 6;
  int n = blockIdx.x * 4 + rw;
  int idx = (int)(unsigned)(minkey[n] & 0xffffffffull);
  const float4* xv = (const float4*)(flat + (size_t)n * D_DIM);
  const float4* ev = (const float4*)(E + (size_t)idx * D_DIM);
  float* emarow = emaw + (size_t)idx * D_DIM;
  float s = 0.f;
#pragma unroll
  for (int t = 0; t < 2; ++t) {
    int p = lane + 64 * t;
    float4 x = xv[p];
    float4 e = ev[p];
    size_t qb = (size_t)OFF_QST + (size_t)n * D_DIM + (size_t)p * 4;
    out[qb + 0] = x.x + (e.x - x.x);
    out[qb + 1] = x.y + (e.y - x.y);
    out[qb + 2] = x.z + (e.z - x.z);
    out[qb + 3] = x.w + (e.w - x.w);
    float dx = e.x - x.x, dy = e.y - x.y, dz = e.z - x.z, dw = e.w - x.w;
    s += dx * dx + dy * dy + dz * dz + dw * dw;
    atomicAdd(emarow + p * 4 + 0, OMD_F * x.x);
    atomicAdd(emarow + p * 4 + 1, OMD_F * x.y);
    atomicAdd(emarow + p * 4 + 2, OMD_F * x.z);
    atomicAdd(emarow + p * 4 + 3, OMD_F * x.w);
  }
#pragma unroll
  for (int off = 32; off > 0; off >>= 1) s += __shfl_down(s, off, 64);
  __shared__ float ws4[4];
  if (lane == 0) ws4[rw] = s;
  __syncthreads();
  if (tid == 0) atomicAdd(&loss_part[blockIdx.x & 63], ws4[0] + ws4[1] + ws4[2] + ws4[3]);
}

// ---------- decode: indices + one-hot ones (fallback path) ----------
__global__ void k_decode(const unsigned long long* __restrict__ minkey,
                         int* __restrict__ counts, float* __restrict__ out) {
  int n = blockIdx.x * 256 + threadIdx.x;
  int c = (int)(unsigned)(minkey[n] & 0xffffffffull);
  out[OFF_IDX + n] = (float)c;
  atomicAdd(&counts[c], 1);
  out[(size_t)OFF_ENC + (size_t)n * K_DIM + c] = 1.0f;
}

// ---------- cluster-size normalize (+tail patch / +loss for fallback) ----------
__global__ __launch_bounds__(1024) void k_cs(const float* __restrict__ ema_cs,
                                             const int* __restrict__ counts,
                                             const float* __restrict__ loss_part,
                                             float* __restrict__ out, int withLoss,
                                             int patchTail) {
  int tid = threadIdx.x;
  float cs1[4];
  float local = 0.f;
#pragma unroll
  for (int t = 0; t < 4; ++t) {
    int k = tid + 1024 * t;
    cs1[t] = ema_cs[k] * DECAY_F + OMD_F * (float)counts[k];
    local += cs1[t];
  }
  __shared__ float wsum[16];
  float v = local;
#pragma unroll
  for (int off = 32; off > 0; off >>= 1) v += __shfl_down(v, off, 64);
  if ((tid & 63) == 0) wsum[tid >> 6] = v;
  __syncthreads();
  float n_total = 0.f;
#pragma unroll
  for (int t = 0; t < 16; ++t) n_total += wsum[t];
  float scale = n_total / (n_total + (float)K_DIM * EPS_F);
#pragma unroll
  for (int t = 0; t < 4; ++t) {
    int k = tid + 1024 * t;
    out[OFF_NEW_CS + k] = (cs1[t] + EPS_F) * scale;
  }
  if (patchTail && tid == 0 && __float_as_uint(out[75497472])) out[75497472] = 0.f;
  if (withLoss && tid < 64) {
    float lv = loss_part[tid];
#pragma unroll
    for (int off = 32; off > 0; off >>= 1) lv += __shfl_down(lv, off, 64);
    if (tid == 0) out[OFF_LOSS] = COMMIT_F * lv / 8388608.0f;
  }
}

// ---------- fallback: new_embedding_weight = new_ema_w / new_cluster_size ----------
__global__ void k_final(float* __restrict__ out) {
  int i = blockIdx.x * 256 + threadIdx.x;
  int k = i >> 9;
  out[OFF_NEW_W + i] = out[OFF_NEW_EMA + i] / out[OFF_NEW_CS + k];
}

extern "C" void kernel_launch(void* const* d_in, const int* in_sizes, int n_in,
                              void* d_out, int out_size, void* d_ws, size_t ws_size,
                              hipStream_t stream) {
  (void)in_sizes; (void)n_in; (void)out_size;
  const float* flat = (const float*)d_in[0];
  const float* E = (const float*)d_in[1];
  const float* ema_w = (const float*)d_in[2];
  const float* ema_cs = (const float*)d_in[3];
  float* out = (float*)d_out;
  char* ws = (char*)d_ws;

  unsigned long long* minkey = (unsigned long long*)(ws + WS_MINKEY);
  int* counts = (int*)(ws + WS_COUNTS);
  float* e2 = (float*)(ws + WS_E2);
  float* loss_part = (float*)(ws + WS_LOSSP);
  int* rcnt = (int*)(ws + WS_RCNT);
  int* offs = (int*)(ws + WS_OFFS);
  int* cursor = (int*)(ws + WS_CURS);
  int* rowl = (int*)(ws + WS_ROWL);

  const bool big = ws_size >= (size_t)WS_NEED;
  char* arena = big ? (ws + WS_ARENA) : (char*)(out + SCR0);
  unsigned long long* m1k = (unsigned long long*)(arena + AR_M1K);
  float* m2v = (float*)(arena + AR_M2V);
  char* xhi = arena + AR_XHI;
  char* ehi = arena + AR_EHI;
  int* rrows = (int*)(arena + AR_RROW);
  float* rcut = (float*)(arena + AR_RCUT);

  k_e2<<<1024, 256, 0, stream>>>(E, e2, (uint4*)ehi, counts, loss_part, rcnt);
  k_conv<<<4096, 256, 0, stream>>>(flat, (uint4*)xhi);
  if (big) {
    // 128 main columns + 64 cleaner columns (x32 = 2048 chunks, all of ENC)
    k_gemm<<<dim3(192, 32), 256, 65536, stream>>>(xhi, ehi, e2, m1k, m2v, out, 1);
    k_reduce<<<64, 256, 0, stream>>>(m1k, m2v, minkey, rcnt, rrows, rcut);
    k_rescue<<<2048, 256, 0, stream>>>(flat, E, e2, rcnt, rrows, rcut, m1k, minkey);
    k_prefix<<<1, 1024, 0, stream>>>(minkey, counts, offs, cursor);
    k_scatter<<<64, 256, 0, stream>>>(minkey, cursor, rowl);
    k_cs<<<1, 1024, 0, stream>>>(ema_cs, counts, loss_part, out, 0, 1);
    k_qdw<<<4096, 256, 0, stream>>>(flat, E, ema_w, counts, offs, rowl, out, loss_part);
    k_loss<<<1, 64, 0, stream>>>(loss_part, out);
  } else {
    k_scale_emaw<<<8192, 256, 0, stream>>>(ema_w, out);
    k_gemm<<<dim3(128, 32), 256, 65536, stream>>>(xhi, ehi, e2, m1k, m2v, out, 0);
    k_reduce<<<64, 256, 0, stream>>>(m1k, m2v, minkey, rcnt, rrows, rcut);
    k_rescue<<<2048, 256, 0, stream>>>(flat, E, e2, rcnt, rrows, rcut, m1k, minkey);
    k_zero<<<16384, 256, 0, stream>>>(out);
    k_decode<<<64, 256, 0, stream>>>(minkey, counts, out);
    k_quant<<<4096, 256, 0, stream>>>(flat, E, minkey, out, out + OFF_NEW_EMA, loss_part);
    k_cs<<<1, 1024, 0, stream>>>(ema_cs, counts, loss_part, out, 1, 0);
    k_final<<<8192, 256, 0, stream>>>(out);
  }
}

// Round 14
// 385.703 us; speedup vs baseline: 1.0089x; 1.0089x over previous
//
#include <hip/hip_runtime.h>
#include <hip/hip_bf16.h>
#include <cstdint>
#include <cstddef>

typedef __attribute__((ext_vector_type(8))) short short8;
typedef __attribute__((ext_vector_type(4))) float f32x4;
typedef __attribute__((ext_vector_type(4))) unsigned int u32x4;

#define D_DIM 512
#define K_DIM 4096
#define N_ROWS 16384  // S*B

#define DECAY_F 0.99f
#define OMD_F 0.01f
#define EPS_F 1e-5f
#define COMMIT_F 0.25f
#define MARGIN_F 0.75f

// d_out offsets (floats), return-order concat
#define OFF_LOSS 0
#define OFF_QST 1
#define OFF_ENC (1 + 8388608)            // 8388609
#define OFF_IDX (OFF_ENC + 67108864)     // 75497473
#define OFF_NEW_W (OFF_IDX + 16384)      // 75513857
#define OFF_NEW_CS (OFF_NEW_W + 2097152) // 77611009
#define OFF_NEW_EMA (OFF_NEW_CS + 4096)  // 77615105

// ENC f32x4 span: floats [8388612, 75497472) -> 16777215 vectors; tail float
// 75497472 patched in k_cs; head floats 8388609..11 patched by cleaner 0.
#define ENC4_CNT 16777215
#define CHUNK4 8192  // f32x4 per cleaner chunk (128 KB); 2048 chunks total

// small ws scratch (bytes)
#define WS_MINKEY 0        // u64*16384 = 131072
#define WS_COUNTS 131072   // int*4096
#define WS_E2 147456       // f32*4096
#define WS_LOSSP 163840    // f32*64
#define WS_RCNT 164096     // int (+pad)
#define WS_OFFS 164112     // int*4096
#define WS_CURS 180496     // int*4096
#define WS_ROWL 196880     // int*16384
#define WS_ARENA 262416    // big arena when ws_size allows

// big arena layout (byte offsets within arena, all 16B-aligned)
#define AR_M1K 0           // u64[16384][32] = 4 MB
#define AR_M2V 4194304     // f32[16384][32] = 2 MB
#define AR_XHI 6291456     // bf16[16384][512] = 16 MB
#define AR_EHI 23068672    // bf16[4096][512] = 4 MB
#define AR_RROW 27262976   // int[16384]
#define AR_RCUT 27328512   // f32[16384]
#define AR_NEED 27394048
#define WS_NEED (WS_ARENA + AR_NEED)

// fallback arena inside one-hot region (float offset; byte 16B-aligned)
#define SCR0 8388612

// ---------------- helpers ----------------
__device__ __forceinline__ unsigned long long mkkey(float d, int c) {
  unsigned u = __float_as_uint(d);
  u ^= (unsigned)(((int)u) >> 31) | 0x80000000u;  // monotone total order
  return ((unsigned long long)u << 32) | (unsigned)c;
}
__device__ __forceinline__ float keyval(unsigned long long k) {
  unsigned u = (unsigned)(k >> 32);
  u = (u & 0x80000000u) ? (u ^ 0x80000000u) : ~u;
  return __uint_as_float(u);
}
// merge (k1,v2) with (ko,v2o): second smallest of union = min(max(v1,v1o), v2, v2o)
__device__ __forceinline__ void merge2(unsigned long long& k1, float& v2,
                                       unsigned long long ko, float v2o) {
  float v1 = keyval(k1), v1o = keyval(ko);
  float vmax = fmaxf(v1, v1o);
  v2 = fminf(fminf(v2, v2o), vmax);
  if (ko < k1) k1 = ko;
}
__device__ __forceinline__ unsigned pk2o(float a, float b) {
  unsigned ua = (__float_as_uint(a) + 0x8000u) & 0xFFFF0000u;
  unsigned ub = (__float_as_uint(b) + 0x8000u) & 0xFFFF0000u;
  return (ua >> 16) | ub;
}
__device__ __forceinline__ void gl_lds16(const void* g, void* l) {
  __builtin_amdgcn_global_load_lds(
      (const __attribute__((address_space(1))) unsigned int*)g,
      (__attribute__((address_space(3))) unsigned int*)l, 16, 0, 0);
}

// batched check-and-skip clean (read channel; steady-state writes ~0)
__device__ __forceinline__ void enc_check(float* __restrict__ out, int cid) {
  const f32x4 z = {0.f, 0.f, 0.f, 0.f};
  const u32x4* p = (const u32x4*)(out + 8388612);
  const int tid = threadIdx.x;
  const int base = cid * CHUNK4 + tid;
#pragma unroll
  for (int h = 0; h < 2; ++h) {
    u32x4 v[16];
#pragma unroll
    for (int t = 0; t < 16; ++t) {
      int i = base + (h * 16 + t) * 256;
      int ii = (i < ENC4_CNT) ? i : 0;
      v[t] = __builtin_nontemporal_load(p + ii);
    }
#pragma unroll
    for (int t = 0; t < 16; ++t) {
      int i = base + (h * 16 + t) * 256;
      if (i < ENC4_CNT && (v[t].x | v[t].y | v[t].z | v[t].w))
        *(f32x4*)(p + i) = z;
    }
  }
  if (cid == 0 && tid == 0) {
    if (__float_as_uint(out[8388609])) out[8388609] = 0.f;
    if (__float_as_uint(out[8388610])) out[8388610] = 0.f;
    if (__float_as_uint(out[8388611])) out[8388611] = 0.f;
  }
}

// pure fire-and-forget NT-store zero (write channel)
__device__ __forceinline__ void enc_blind(float* __restrict__ out, int cid) {
  const f32x4 z = {0.f, 0.f, 0.f, 0.f};
  f32x4* p = (f32x4*)(out + 8388612);
  const int base = cid * CHUNK4 + threadIdx.x;
#pragma unroll
  for (int t = 0; t < 32; ++t) {
    int i = base + t * 256;
    if (i < ENC4_CNT) __builtin_nontemporal_store(z, p + i);
  }
}

// ---------- codebook norms + E->bf16 + zero counts/loss/rcnt ----------
__global__ void k_e2(const float* __restrict__ E, float* __restrict__ e2,
                     uint4* __restrict__ ehi, int* __restrict__ counts,
                     float* __restrict__ loss_part, int* __restrict__ rcnt) {
  int tid = threadIdx.x;
  int lane = tid & 63;
  int w = tid >> 6;
  int k = blockIdx.x * 4 + w;
  if (tid < 4) counts[blockIdx.x * 4 + tid] = 0;
  if (blockIdx.x == 0 && tid < 64) loss_part[tid] = 0.f;
  if (blockIdx.x == 1 && tid == 0) *rcnt = 0;
  const float4* ev = (const float4*)(E + (size_t)k * D_DIM);
  float4 a = ev[lane * 2], b = ev[lane * 2 + 1];
  uint4 h;
  h.x = pk2o(a.x, a.y);
  h.y = pk2o(a.z, a.w);
  h.z = pk2o(b.x, b.y);
  h.w = pk2o(b.z, b.w);
  ehi[(size_t)k * 64 + lane] = h;
  float s = a.x * a.x + a.y * a.y + a.z * a.z + a.w * a.w +
            b.x * b.x + b.y * b.y + b.z * b.z + b.w * b.w;
#pragma unroll
  for (int off = 32; off > 0; off >>= 1) s += __shfl_down(s, off, 64);
  if (lane == 0) e2[k] = s;
}

// ---------- f32 -> hi bf16 (8 elems / thread) ----------
__global__ void k_conv(const float* __restrict__ src, uint4* __restrict__ hi) {
  int t = blockIdx.x * 256 + threadIdx.x;
  const float4* s4 = (const float4*)src;
  float4 a = s4[t * 2], b = s4[t * 2 + 1];
  uint4 h;
  h.x = pk2o(a.x, a.y);
  h.y = pk2o(a.z, a.w);
  h.z = pk2o(b.x, b.y);
  h.w = pk2o(b.z, b.w);
  hi[t] = h;
}

// ---------- new_ema_w := DECAY * ema_w (fallback path only) ----------
__global__ void k_scale_emaw(const float* __restrict__ ema_w, float* __restrict__ out) {
  int i = blockIdx.x * 256 + threadIdx.x;
  out[OFF_NEW_EMA + i] = DECAY_F * ema_w[i];
}

// ---------- bf16-hi MFMA distance GEMM + per-block top-2 argmin + cleaners ----------
// main blocks: bx < 128. cleaner blocks: bx in [128,192) -> cid = (bx-128)*32+by.
// even cid: check-and-skip (read channel); odd cid: blind NT-store (write channel).
__global__ __launch_bounds__(256, 2) void k_gemm(
    const char* __restrict__ xhi, const char* __restrict__ ehi,
    const float* __restrict__ e2, unsigned long long* __restrict__ m1k,
    float* __restrict__ m2v, float* outp, int withClean) {
  if (blockIdx.x >= 128) {
    int cid = ((int)blockIdx.x - 128) * 32 + (int)blockIdx.y;
    if (cid & 1) enc_blind(outp, cid);
    else enc_check(outp, cid);
    return;
  }
  extern __shared__ char smem[];  // 65536
  const int tid = threadIdx.x;
  const int w = tid >> 6, lane = tid & 63;
  const int wr = w >> 1, wc = w & 1;
  const int l15 = lane & 15, g = lane >> 4;
  const int row0 = blockIdx.x * 128;
  const int col0 = blockIdx.y * 128;
  (void)withClean;

  const char* srcBase = (w < 2) ? xhi : ehi;
  const int srcRow0 = (w < 2) ? (row0 + 64 * w) : (col0 + 64 * (w - 2));
  const int lr = lane >> 3;  // row within 8-row group
  const int lc = lane & 7;   // dest slot
  const char* srcLane = srcBase + (size_t)(srcRow0 + lr) * 1024 + ((lc ^ lr) << 4);
  const int dstOff = w * 8192;

#define STAGE(c, b)                                       \
  {                                                       \
    const char* sp_ = srcLane + (c) * 128;                \
    char* lb_ = smem + (b) * 32768 + dstOff;              \
    _Pragma("unroll") for (int q = 0; q < 8; ++q)         \
        gl_lds16(sp_ + q * 8192, lb_ + q * 1024);         \
  }

  f32x4 acc[4][4];
  const f32x4 z = {0.f, 0.f, 0.f, 0.f};
#pragma unroll
  for (int i = 0; i < 4; ++i)
#pragma unroll
    for (int j = 0; j < 4; ++j) acc[i][j] = z;

  STAGE(0, 0);
  const int s0 = (g ^ (l15 & 7)) << 4;
  const int aRow = (wr * 64 + l15) * 128;
  const int bRow = (wc * 64 + l15) * 128;

  for (int c = 0; c < 8; ++c) {
    __syncthreads();
    if (c < 7) STAGE(c + 1, (c + 1) & 1);
    const char* Ab = smem + (c & 1) * 32768;
    const char* Bb = Ab + 16384;
    short8 a[2][4], b[2][4];
#pragma unroll
    for (int kk = 0; kk < 2; ++kk) {
      const int sw = s0 ^ (kk << 6);
#pragma unroll
      for (int i = 0; i < 4; ++i) {
        a[kk][i] = *(const short8*)(Ab + aRow + i * 2048 + sw);
        b[kk][i] = *(const short8*)(Bb + bRow + i * 2048 + sw);
      }
    }
#pragma unroll
    for (int kk = 0; kk < 2; ++kk)
#pragma unroll
      for (int i = 0; i < 4; ++i)
#pragma unroll
        for (int j = 0; j < 4; ++j)
          acc[i][j] = __builtin_amdgcn_mfma_f32_16x16x32_bf16(a[kk][i], b[kk][j], acc[i][j], 0, 0, 0);
  }
#undef STAGE

  __syncthreads();
  unsigned long long* lk = (unsigned long long*)smem;  // [128][2]
  float* lv = (float*)(smem + 2048);                   // [128][2]
  float e2v[4];
#pragma unroll
  for (int j = 0; j < 4; ++j) e2v[j] = e2[col0 + wc * 64 + j * 16 + l15];

#pragma unroll
  for (int i = 0; i < 4; ++i) {
    int rowl = wr * 64 + i * 16 + (g << 2);
#pragma unroll
    for (int r = 0; r < 4; ++r) {
      unsigned long long k1 = 0;
      float v2 = 3.4e38f;
#pragma unroll
      for (int j = 0; j < 4; ++j) {
        float dv = fmaf(-2.f, acc[i][j][r], e2v[j]);
        unsigned long long kk = mkkey(dv, col0 + wc * 64 + j * 16 + l15);
        if (j == 0) k1 = kk;
        else merge2(k1, v2, kk, 3.4e38f);
      }
#pragma unroll
      for (int m = 1; m <= 8; m <<= 1) {
        unsigned long long ko = __shfl_xor(k1, m, 64);
        float vo = __shfl_xor(v2, m, 64);
        merge2(k1, v2, ko, vo);
      }
      if (l15 == 0) {
        lk[(rowl + r) * 2 + wc] = k1;
        lv[(rowl + r) * 2 + wc] = v2;
      }
    }
  }
  __syncthreads();
  if (tid < 128) {
    unsigned long long k1 = lk[tid * 2];
    float v2 = lv[tid * 2];
    merge2(k1, v2, lk[tid * 2 + 1], lv[tid * 2 + 1]);
    size_t o = (size_t)(row0 + tid) * 32 + blockIdx.y;
    m1k[o] = k1;
    m2v[o] = v2;
  }
}

// ---------- per-row reduce over 32 blocks; flag near-ties for rescue ----------
__global__ void k_reduce(const unsigned long long* __restrict__ m1k,
                         const float* __restrict__ m2v,
                         unsigned long long* __restrict__ minkey,
                         int* __restrict__ rcnt, int* __restrict__ rrows,
                         float* __restrict__ rcut) {
  int row = blockIdx.x * 256 + threadIdx.x;
  const unsigned long long* kp = m1k + (size_t)row * 32;
  const float* vp = m2v + (size_t)row * 32;
  unsigned long long k1 = kp[0];
  float v2 = vp[0];
#pragma unroll 4
  for (int t = 1; t < 32; ++t) merge2(k1, v2, kp[t], vp[t]);
  float v1 = keyval(k1);
  if (v2 - v1 < MARGIN_F) {
    minkey[row] = ~0ull;  // reset for exact atomicMin
    int p = atomicAdd(rcnt, 1);
    rrows[p] = row;
    rcut[p] = v1 + MARGIN_F;
  } else {
    minkey[row] = k1;
  }
}

// ---------- exact f32 re-scan for flagged rows, filtered by per-block min ----------
__global__ __launch_bounds__(256) void k_rescue(
    const float* __restrict__ flat, const float* __restrict__ E,
    const float* __restrict__ e2, const int* __restrict__ rcnt,
    const int* __restrict__ rrows, const float* __restrict__ rcut,
    const unsigned long long* __restrict__ m1k,
    unsigned long long* __restrict__ minkey) {
  __shared__ float sx[512];
  __shared__ unsigned long long skey[16];
  const int tid = threadIdx.x;
  const int sl = tid & 15;
  int cnt = *rcnt;
  if (cnt > N_ROWS) cnt = N_ROWS;
  for (int j = (int)blockIdx.x; j < cnt; j += (int)gridDim.x) {
    const int row = rrows[j];
    const float cutoff = rcut[j];
    __syncthreads();
    if (tid < 128) ((float4*)sx)[tid] = ((const float4*)(flat + (size_t)row * 512))[tid];
    __syncthreads();
    unsigned long long best = ~0ull;
    for (int b = 0; b < 32; ++b) {
      if (keyval(m1k[(size_t)row * 32 + b]) >= cutoff) continue;
      const int c0 = b * 128 + (tid >> 4);
#pragma unroll 2
      for (int p = 0; p < 8; ++p) {
        const int c = c0 + p * 16;
        const float4* ev = (const float4*)(E + (size_t)c * 512) + sl * 8;
        const float4* xv = (const float4*)sx + sl * 8;
        float s = 0.f;
#pragma unroll
        for (int q = 0; q < 8; ++q) {
          float4 e4 = ev[q];
          float4 x4 = xv[q];
          s = fmaf(e4.x, x4.x, s);
          s = fmaf(e4.y, x4.y, s);
          s = fmaf(e4.z, x4.z, s);
          s = fmaf(e4.w, x4.w, s);
        }
#pragma unroll
        for (int m = 1; m <= 8; m <<= 1) s += __shfl_xor(s, m, 64);
        if (sl == 0) {
          unsigned long long k = mkkey(fmaf(-2.f, s, e2[c]), c);
          if (k < best) best = k;
        }
      }
    }
    if (sl == 0) skey[tid >> 4] = best;
    __syncthreads();
    if (tid == 0) {
      unsigned long long m = skey[0];
#pragma unroll
      for (int t = 1; t < 16; ++t)
        if (skey[t] < m) m = skey[t];
      atomicMin(&minkey[row], m);
    }
  }
}

// ---------- fallback path: bulk zero ----------
__global__ void k_zero(float* __restrict__ out) {
  const f32x4 z = {0.f, 0.f, 0.f, 0.f};
  f32x4* out4 = (f32x4*)(out + 8388612);
#pragma unroll
  for (int t = 0; t < 4; ++t) {
    int i = blockIdx.x * 1024 + t * 256 + threadIdx.x;
    if (i < 16777215) __builtin_nontemporal_store(z, out4 + i);
  }
  if (blockIdx.x == 0 && threadIdx.x == 0) {
    out[8388609] = 0.f;
    out[8388610] = 0.f;
    out[8388611] = 0.f;
    out[75497472] = 0.f;
  }
}

// ---------- counts (LDS histogram) + exclusive prefix -> offs, cursor ----------
__global__ __launch_bounds__(1024) void k_prefix(const unsigned long long* __restrict__ minkey,
                                                 int* __restrict__ counts,
                                                 int* __restrict__ offs,
                                                 int* __restrict__ cursor) {
  __shared__ int lc[4096];
  __shared__ int wsum[16];
  const int tid = threadIdx.x;
  const int lane = tid & 63, w = tid >> 6;
#pragma unroll
  for (int t = 0; t < 4; ++t) lc[tid * 4 + t] = 0;
  __syncthreads();
#pragma unroll
  for (int t = 0; t < 16; ++t) {
    int c = (int)(unsigned)(minkey[tid + 1024 * t] & 0xffffffffull);
    atomicAdd(&lc[c], 1);
  }
  __syncthreads();
  int v[4];
  int loc = 0;
#pragma unroll
  for (int t = 0; t < 4; ++t) {
    v[t] = lc[tid * 4 + t];
    loc += v[t];
  }
  int scan = loc;
#pragma unroll
  for (int off = 1; off <= 32; off <<= 1) {
    int o = __shfl_up(scan, off, 64);
    if (lane >= off) scan += o;
  }
  if (lane == 63) wsum[w] = scan;
  __syncthreads();
  int base = 0;
  for (int i = 0; i < w; ++i) base += wsum[i];
  int run = base + scan - loc;
#pragma unroll
  for (int t = 0; t < 4; ++t) {
    counts[tid * 4 + t] = v[t];
    offs[tid * 4 + t] = run;
    cursor[tid * 4 + t] = run;
    run += v[t];
  }
}

// ---------- scatter row ids into cluster buckets ----------
__global__ void k_scatter(const unsigned long long* __restrict__ minkey,
                          int* __restrict__ cursor, int* __restrict__ rowl) {
  int n = blockIdx.x * 256 + threadIdx.x;
  int c = (int)(unsigned)(minkey[n] & 0xffffffffull);
  int pos = atomicAdd(&cursor[c], 1);
  rowl[pos] = n;
}

// ---------- fused per-code pass: QST + loss + new_ema_w/new_w + IDX + ENC ones ----------
__global__ __launch_bounds__(256) void k_qdw(const float* __restrict__ flat,
                                             const float* __restrict__ E,
                                             const float* __restrict__ ema_w,
                                             const int* __restrict__ counts,
                                             const int* __restrict__ offs,
                                             const int* __restrict__ rowl,
                                             float* __restrict__ out,
                                             float* __restrict__ loss_part) {
  const int k = blockIdx.x;
  const int tid = threadIdx.x;
  const int cnt = counts[k];
  const int off = offs[k];
  const int d0 = tid * 2;
  const float ex = E[(size_t)k * D_DIM + d0];
  const float ey = E[(size_t)k * D_DIM + d0 + 1];
  float s0 = 0.f, s1 = 0.f, lsum = 0.f;
  for (int i = 0; i < cnt; ++i) {
    int r = rowl[off + i];
    const float* xr = flat + (size_t)r * D_DIM + d0;
    float xx = xr[0], xy = xr[1];
    size_t qb = (size_t)OFF_QST + (size_t)r * D_DIM + d0;
    out[qb] = xx + (ex - xx);
    out[qb + 1] = xy + (ey - xy);
    float dx = ex - xx, dy = ey - xy;
    lsum += dx * dx + dy * dy;
    s0 += xx;
    s1 += xy;
  }
  // indices + one-hot ones for this bucket
  for (int i = tid; i < cnt; i += 256) {
    int r = rowl[off + i];
    out[OFF_IDX + r] = (float)k;
    out[(size_t)OFF_ENC + (size_t)r * K_DIM + k] = 1.0f;
  }
  // dw finalize
  float e0 = DECAY_F * ema_w[(size_t)k * D_DIM + d0] + OMD_F * s0;
  float e1 = DECAY_F * ema_w[(size_t)k * D_DIM + d0 + 1] + OMD_F * s1;
  float cs = out[OFF_NEW_CS + k];
  size_t b = (size_t)k * D_DIM + d0;
  out[OFF_NEW_EMA + b] = e0;
  out[OFF_NEW_EMA + b + 1] = e1;
  out[OFF_NEW_W + b] = e0 / cs;
  out[OFF_NEW_W + b + 1] = e1 / cs;
  // loss partial reduce
#pragma unroll
  for (int o = 32; o > 0; o >>= 1) lsum += __shfl_down(lsum, o, 64);
  __shared__ float ws4[4];
  if ((tid & 63) == 0) ws4[tid >> 6] = lsum;
  __syncthreads();
  if (tid == 0 && cnt > 0)
    atomicAdd(&loss_part[k & 63], ws4[0] + ws4[1] + ws4[2] + ws4[3]);
}

// ---------- loss finalize (big path) ----------
__global__ void k_loss(const float* __restrict__ loss_part, float* __restrict__ out) {
  float lv = loss_part[threadIdx.x];
#pragma unroll
  for (int off = 32; off > 0; off >>= 1) lv += __shfl_down(lv, off, 64);
  if (threadIdx.x == 0) out[OFF_LOSS] = COMMIT_F * lv / 8388608.0f;
}

// ---------- gather quantized, STE out, loss partials, dw atomics (fallback) ----------
__global__ void k_quant(const float* __restrict__ flat, const float* __restrict__ E,
                        const unsigned long long* __restrict__ minkey,
                        float* __restrict__ out, float* emaw,
                        float* __restrict__ loss_part) {
  int tid = threadIdx.x;
  int lane = tid & 63;
  int rw = tid >> 6;
  int n = blockIdx.x * 4 + rw;
  int idx = (int)(unsigned)(minkey[n] & 0xffffffffull);
  const float4* xv = (const float4*)(flat + (size_t)n * D_DIM);
  const float4* ev = (const float4*)(E + (size_t)idx * D_DIM);
  float* emarow = emaw + (size_t)idx * D_DIM;
  float s = 0.f;
#pragma unroll
  for (int t = 0; t < 2; ++t) {
    int p = lane + 64 * t;
    float4 x = xv[p];
    float4 e = ev[p];
    size_t qb = (size_t)OFF_QST + (size_t)n * D_DIM + (size_t)p * 4;
    out[qb + 0] = x.x + (e.x - x.x);
    out[qb + 1] = x.y + (e.y - x.y);
    out[qb + 2] = x.z + (e.z - x.z);
    out[qb + 3] = x.w + (e.w - x.w);
    float dx = e.x - x.x, dy = e.y - x.y, dz = e.z - x.z, dw = e.w - x.w;
    s += dx * dx + dy * dy + dz * dz + dw * dw;
    atomicAdd(emarow + p * 4 + 0, OMD_F * x.x);
    atomicAdd(emarow + p * 4 + 1, OMD_F * x.y);
    atomicAdd(emarow + p * 4 + 2, OMD_F * x.z);
    atomicAdd(emarow + p * 4 + 3, OMD_F * x.w);
  }
#pragma unroll
  for (int off = 32; off > 0; off >>= 1) s += __shfl_down(s, off, 64);
  __shared__ float ws4[4];
  if (lane == 0) ws4[rw] = s;
  __syncthreads();
  if (tid == 0) atomicAdd(&loss_part[blockIdx.x & 63], ws4[0] + ws4[1] + ws4[2] + ws4[3]);
}

// ---------- decode: indices + one-hot ones (fallback path) ----------
__global__ void k_decode(const unsigned long long* __restrict__ minkey,
                         int* __restrict__ counts, float* __restrict__ out) {
  int n = blockIdx.x * 256 + threadIdx.x;
  int c = (int)(unsigned)(minkey[n] & 0xffffffffull);
  out[OFF_IDX + n] = (float)c;
  atomicAdd(&counts[c], 1);
  out[(size_t)OFF_ENC + (size_t)n * K_DIM + c] = 1.0f;
}

// ---------- cluster-size normalize (+tail patch / +loss for fallback) ----------
__global__ __launch_bounds__(1024) void k_cs(const float* __restrict__ ema_cs,
                                             const int* __restrict__ counts,
                                             const float* __restrict__ loss_part,
                                             float* __restrict__ out, int withLoss,
                                             int patchTail) {
  int tid = threadIdx.x;
  float cs1[4];
  float local = 0.f;
#pragma unroll
  for (int t = 0; t < 4; ++t) {
    int k = tid + 1024 * t;
    cs1[t] = ema_cs[k] * DECAY_F + OMD_F * (float)counts[k];
    local += cs1[t];
  }
  __shared__ float wsum[16];
  float v = local;
#pragma unroll
  for (int off = 32; off > 0; off >>= 1) v += __shfl_down(v, off, 64);
  if ((tid & 63) == 0) wsum[tid >> 6] = v;
  __syncthreads();
  float n_total = 0.f;
#pragma unroll
  for (int t = 0; t < 16; ++t) n_total += wsum[t];
  float scale = n_total / (n_total + (float)K_DIM * EPS_F);
#pragma unroll
  for (int t = 0; t < 4; ++t) {
    int k = tid + 1024 * t;
    out[OFF_NEW_CS + k] = (cs1[t] + EPS_F) * scale;
  }
  if (patchTail && tid == 0 && __float_as_uint(out[75497472])) out[75497472] = 0.f;
  if (withLoss && tid < 64) {
    float lv = loss_part[tid];
#pragma unroll
    for (int off = 32; off > 0; off >>= 1) lv += __shfl_down(lv, off, 64);
    if (tid == 0) out[OFF_LOSS] = COMMIT_F * lv / 8388608.0f;
  }
}

// ---------- fallback: new_embedding_weight = new_ema_w / new_cluster_size ----------
__global__ void k_final(float* __restrict__ out) {
  int i = blockIdx.x * 256 + threadIdx.x;
  int k = i >> 9;
  out[OFF_NEW_W + i] = out[OFF_NEW_EMA + i] / out[OFF_NEW_CS + k];
}

extern "C" void kernel_launch(void* const* d_in, const int* in_sizes, int n_in,
                              void* d_out, int out_size, void* d_ws, size_t ws_size,
                              hipStream_t stream) {
  (void)in_sizes; (void)n_in; (void)out_size;
  const float* flat = (const float*)d_in[0];
  const float* E = (const float*)d_in[1];
  const float* ema_w = (const float*)d_in[2];
  const float* ema_cs = (const float*)d_in[3];
  float* out = (float*)d_out;
  char* ws = (char*)d_ws;

  unsigned long long* minkey = (unsigned long long*)(ws + WS_MINKEY);
  int* counts = (int*)(ws + WS_COUNTS);
  float* e2 = (float*)(ws + WS_E2);
  float* loss_part = (float*)(ws + WS_LOSSP);
  int* rcnt = (int*)(ws + WS_RCNT);
  int* offs = (int*)(ws + WS_OFFS);
  int* cursor = (int*)(ws + WS_CURS);
  int* rowl = (int*)(ws + WS_ROWL);

  const bool big = ws_size >= (size_t)WS_NEED;
  char* arena = big ? (ws + WS_ARENA) : (char*)(out + SCR0);
  unsigned long long* m1k = (unsigned long long*)(arena + AR_M1K);
  float* m2v = (float*)(arena + AR_M2V);
  char* xhi = arena + AR_XHI;
  char* ehi = arena + AR_EHI;
  int* rrows = (int*)(arena + AR_RROW);
  float* rcut = (float*)(arena + AR_RCUT);

  k_e2<<<1024, 256, 0, stream>>>(E, e2, (uint4*)ehi, counts, loss_part, rcnt);
  k_conv<<<4096, 256, 0, stream>>>(flat, (uint4*)xhi);
  if (big) {
    // 128 main columns + 64 cleaner columns (x32 = 2048 chunks, all of ENC)
    k_gemm<<<dim3(192, 32), 256, 65536, stream>>>(xhi, ehi, e2, m1k, m2v, out, 1);
    k_reduce<<<64, 256, 0, stream>>>(m1k, m2v, minkey, rcnt, rrows, rcut);
    k_rescue<<<2048, 256, 0, stream>>>(flat, E, e2, rcnt, rrows, rcut, m1k, minkey);
    k_prefix<<<1, 1024, 0, stream>>>(minkey, counts, offs, cursor);
    k_scatter<<<64, 256, 0, stream>>>(minkey, cursor, rowl);
    k_cs<<<1, 1024, 0, stream>>>(ema_cs, counts, loss_part, out, 0, 1);
    k_qdw<<<4096, 256, 0, stream>>>(flat, E, ema_w, counts, offs, rowl, out, loss_part);
    k_loss<<<1, 64, 0, stream>>>(loss_part, out);
  } else {
    k_scale_emaw<<<8192, 256, 0, stream>>>(ema_w, out);
    k_gemm<<<dim3(128, 32), 256, 65536, stream>>>(xhi, ehi, e2, m1k, m2v, out, 0);
    k_reduce<<<64, 256, 0, stream>>>(m1k, m2v, minkey, rcnt, rrows, rcut);
    k_rescue<<<2048, 256, 0, stream>>>(flat, E, e2, rcnt, rrows, rcut, m1k, minkey);
    k_zero<<<16384, 256, 0, stream>>>(out);
    k_decode<<<64, 256, 0, stream>>>(minkey, counts, out);
    k_quant<<<4096, 256, 0, stream>>>(flat, E, minkey, out, out + OFF_NEW_EMA, loss_part);
    k_cs<<<1, 1024, 0, stream>>>(ema_cs, counts, loss_part, out, 1, 0);
    k_final<<<8192, 256, 0, stream>>>(out);
  }
}